// Round 2
// baseline (395.823 us; speedup 1.0000x reference)
//
#include <hip/hip_runtime.h>
#include <cstdint>

#define NPOS   32768   // B*H*W
#define KCODE  1024
#define DDIM   256

typedef __attribute__((ext_vector_type(16))) float f32x16;

// wave-uniform scalar load: 16 dwords -> 16 SGPRs. OFF is a byte immediate
// (21-bit signed on gfx950 SMEM). p must be wave-uniform.
template<int OFF>
__device__ __forceinline__ f32x16 sload16(const float* p) {
  f32x16 r;
  asm volatile("s_load_dwordx16 %0, %1, %2" : "=s"(r) : "s"(p), "i"(OFF));
  return r;
}

// waitcnt that data-ties the loaded SGPR tuples so no use can be scheduled
// before the wait completes.
#define KWAIT4(a,b,c,d) \
  asm volatile("s_waitcnt lgkmcnt(0)" : "+s"(a), "+s"(b), "+s"(c), "+s"(d) :: "memory")

// ---- kernel 0: wsq[k] = sum_d w[k][d]^2 ------------------------------------
__global__ void wsq_kernel(const float* __restrict__ w, float* __restrict__ wsq) {
  const int k = blockIdx.x;       // 1024
  const int lane = threadIdx.x;   // 64
  float4 v = *(const float4*)(w + (size_t)k * DDIM + lane * 4);
  float s = v.x * v.x + v.y * v.y + v.z * v.z + v.w * v.w;
  #pragma unroll
  for (int off = 32; off > 0; off >>= 1) s += __shfl_down(s, off, 64);
  if (lane == 0) wsq[k] = s;
}

// ---- kernel 0b: pair-interleaved transpose wt2[p][k][i] = w[k][2p+i] -------
// so one s_load_dwordx16 at (p*2048 + k0*2)*4B yields 8 k x 2 d contiguous.
__global__ void wt2_kernel(const float* __restrict__ w, float* __restrict__ wt2) {
  const int k = blockIdx.x;        // 1024
  const int d = threadIdx.x;       // 256
  float v = w[k * DDIM + d];
  wt2[(size_t)(d >> 1) * 2048 + k * 2 + (d & 1)] = v;
}

// ---- kernel 1: fused dist-GEMM + argmin, scalar-w --------------------------
// dist(n,k) = wsq[k] - 2 * x_n . w_k
// Block: 64 n, 512 threads (8 waves). Wave wv owns k in [wv*128, wv*128+128).
// All 64 lanes of a wave share (d,k); lane l <-> n0+l. w comes in via SMEM.
__global__ __launch_bounds__(512, 4) void argmin_kernel(
    const float* __restrict__ z, const float* __restrict__ wt2,
    const float* __restrict__ wsq, int* __restrict__ idxout) {
  __shared__ __align__(16) float As[64 * 64 * 4];          // [dc][n][4] 64KB
  __shared__ __align__(16) unsigned long long Red[64 * 8]; // 4KB

  const int tid = threadIdx.x;
  const int l = tid & 63;
  const int wv = __builtin_amdgcn_readfirstlane(tid >> 6);
  const int n0 = blockIdx.x * 64;
  const int b = n0 >> 10;
  const int hw0 = n0 & 1023;
  const float* zb = z + ((size_t)b * DDIM) * 1024 + hw0;

  // stage As[d>>2][n][d&3]: thread t handles n = t&63, d in [(t>>6)*32, +32)
  {
    const int n = tid & 63;
    const int d0 = (tid >> 6) * 32;
    #pragma unroll
    for (int dd = 0; dd < 32; ++dd) {
      const int d = d0 + dd;
      As[(d >> 2) * 256 + n * 4 + (d & 3)] = zb[(size_t)d * 1024 + n];
    }
  }
  __syncthreads();

  unsigned long long best = ~0ull;
  const int k0w = wv * 128;
  const float* wbase = wt2 + (size_t)k0w * 2;

  for (int kc = 0; kc < 8; ++kc) {
    const int k0 = k0w + kc * 16;
    float acc[16];
    #pragma unroll
    for (int j = 0; j < 16; ++j) acc[j] = 0.f;

    const float* wp = wbase + kc * 32;   // + kc*16 k * 2 floats
    #pragma unroll 1
    for (int dc8 = 0; dc8 < 8; ++dc8) {
      #pragma unroll
      for (int u = 0; u < 8; ++u) {
        const int dc = dc8 * 8 + u;
        float4 zv = *(const float4*)(As + dc * 256 + l * 4);
        // d-pairs p0 = 2dc (offset u*16384B), p1 = 2dc+1 (+8192B);
        // second 8 k at +64B
        f32x16 wA = sload16<0 * 8192 +  0>(wp + u * 4096);
        f32x16 wB = sload16<0 * 8192 + 64>(wp + u * 4096);
        f32x16 wC = sload16<1 * 8192 +  0>(wp + u * 4096);
        f32x16 wD = sload16<1 * 8192 + 64>(wp + u * 4096);
        KWAIT4(wA, wB, wC, wD);
        #pragma unroll
        for (int j = 0; j < 8; ++j) {
          acc[j]     += zv.x * wA[2 * j] + zv.y * wA[2 * j + 1]
                      + zv.z * wC[2 * j] + zv.w * wC[2 * j + 1];
          acc[j + 8] += zv.x * wB[2 * j] + zv.y * wB[2 * j + 1]
                      + zv.z * wD[2 * j] + zv.w * wD[2 * j + 1];
        }
      }
      wp += 8 * 4096;   // 8 dc * 16384 bytes
    }

    f32x16 wq = sload16<0>(wsq + k0);
    asm volatile("s_waitcnt lgkmcnt(0)" : "+s"(wq));
    #pragma unroll
    for (int j = 0; j < 16; ++j) {
      float dist = wq[j] - 2.0f * acc[j];
      unsigned u32 = __float_as_uint(dist);
      u32 = (u32 & 0x80000000u) ? ~u32 : (u32 | 0x80000000u);  // monotone order
      unsigned long long key =
          ((unsigned long long)u32 << 32) | (unsigned)(k0 + j);
      best = best < key ? best : key;   // ties -> smallest k
    }
  }

  Red[l * 8 + wv] = best;
  __syncthreads();
  if (tid < 64) {
    unsigned long long m = Red[tid * 8];
    #pragma unroll
    for (int i = 1; i < 8; ++i) {
      unsigned long long v = Red[tid * 8 + i];
      m = v < m ? v : m;
    }
    idxout[n0 + tid] = (int)(m & 0xFFFFFFFFull);
  }
}

// ---- kernel 2: gather + permute-back, writes both outputs ------------------
__global__ void gather_kernel(const float* __restrict__ w, const int* __restrict__ idx,
                              float* __restrict__ out) {
  const int g = blockIdx.x * 256 + threadIdx.x;  // [0, 2097152) float4s
  const int hw4 = g & 255;
  const int c = (g >> 8) & 255;
  const int b = g >> 16;
  int4 kv = *(const int4*)(idx + b * 1024 + hw4 * 4);
  float4 v;
  v.x = w[(size_t)kv.x * 256 + c];
  v.y = w[(size_t)kv.y * 256 + c];
  v.z = w[(size_t)kv.z * 256 + c];
  v.w = w[(size_t)kv.w * 256 + c];
  float4* o = (float4*)out;
  o[g] = v;              // codes
  o[g + 2097152] = v;    // codes_bar (identical forward value)
}

extern "C" void kernel_launch(void* const* d_in, const int* in_sizes, int n_in,
                              void* d_out, int out_size, void* d_ws, size_t ws_size,
                              hipStream_t stream) {
  const float* z = (const float*)d_in[0];   // [32,256,32,32] fp32
  const float* w = (const float*)d_in[1];   // [1024,256] fp32
  float* out = (float*)d_out;

  float* wsq = (float*)d_ws;                              // 4KB @ 0
  int* idx = (int*)((char*)d_ws + 4096);                  // 128KB @ 4KB
  // wt2 needs 1MB: use ws if it fits, else the tail of d_out (gather
  // overwrites it only after argmin has consumed it — stream-ordered).
  float* wt2;
  if (ws_size >= (size_t)(4096 + 131072 + 1048576))
    wt2 = (float*)((char*)d_ws + 4096 + 131072);
  else
    wt2 = out + (size_t)out_size - 262144;

  wsq_kernel<<<KCODE, 64, 0, stream>>>(w, wsq);
  wt2_kernel<<<KCODE, DDIM, 0, stream>>>(w, wt2);
  argmin_kernel<<<NPOS / 64, 512, 0, stream>>>(z, wt2, wsq, idx);
  gather_kernel<<<2097152 / 256, 256, 0, stream>>>(w, idx, out);
}